// Round 1
// baseline (400.993 us; speedup 1.0000x reference)
//
#include <hip/hip_runtime.h>

#define TOKENS 8192
#define D_IN   4096
#define D_OUT  4096

typedef _Float16 f16;
typedef __attribute__((ext_vector_type(8))) _Float16 half8;
typedef __attribute__((ext_vector_type(4))) float    f32x4;

// ---------------- conversion kernels ----------------

__global__ void cvt_x_kernel(const float* __restrict__ x, f16* __restrict__ xh) {
    size_t i = ((size_t)blockIdx.x * blockDim.x + threadIdx.x) * 4;
    float4 v = *reinterpret_cast<const float4*>(x + i);
    union { f16 h[4]; uint2 u; } p;
    p.h[0] = (f16)v.x; p.h[1] = (f16)v.y; p.h[2] = (f16)v.z; p.h[3] = (f16)v.w;
    *reinterpret_cast<uint2*>(xh + i) = p.u;
}

__global__ void cvt_w_kernel(const int* __restrict__ w, f16* __restrict__ wh,
                             const float* __restrict__ scale_p,
                             const int* __restrict__ zp_p) {
    size_t i = ((size_t)blockIdx.x * blockDim.x + threadIdx.x) * 4;
    float s = scale_p[0];
    float z = (float)zp_p[0];
    int4 v = *reinterpret_cast<const int4*>(w + i);
    union { f16 h[4]; uint2 u; } p;
    p.h[0] = (f16)(((float)v.x - z) * s);
    p.h[1] = (f16)(((float)v.y - z) * s);
    p.h[2] = (f16)(((float)v.z - z) * s);
    p.h[3] = (f16)(((float)v.w - z) * s);
    *reinterpret_cast<uint2*>(wh + i) = p.u;
}

// ---------------- GEMM ----------------
// C[t][o] = sum_k A[t][k] * B[o][k]   (A = x_f16 [M][K], B = w_f16 [N][K])
// 128x128 tile, BK=32, 4 waves (2x2), 16x16x32 f16 MFMA, 4x4 frags/wave.

#define BM 128
#define BN 128
#define BK 32

__device__ inline void gload_lds16(const void* g, void* l) {
    __builtin_amdgcn_global_load_lds(
        (const __attribute__((address_space(1))) void*)g,
        (__attribute__((address_space(3))) void*)l, 16, 0, 0);
}

__global__ __launch_bounds__(256, 2)
void gemm_f16_kernel(const f16* __restrict__ A, const f16* __restrict__ B,
                     const float* __restrict__ bias,
                     const float* __restrict__ oscale_p,
                     const int* __restrict__ ozp_p,
                     float* __restrict__ C)
{
    constexpr int M = TOKENS, N = D_OUT, K = D_IN;
    (void)M;
    __shared__ f16 As[BM][BK];
    __shared__ f16 Bs[BN][BK];

    // XCD-aware bijective swizzle (grid = 2048, divisible by 8)
    int nwg = gridDim.x;
    int cpx = nwg >> 3;
    int bid = blockIdx.x;
    int swz = (bid & 7) * cpx + (bid >> 3);
    int ntn = N / BN;                       // 32
    int tm = swz / ntn, tn = swz % ntn;
    int m0 = tm * BM, n0 = tn * BN;

    int tid  = threadIdx.x;
    int lane = tid & 63;
    int wv   = tid >> 6;                    // wave 0..3
    int wr   = wv >> 1, wc = wv & 1;        // 2x2 wave grid

    // staging: per wave, 16 rows x 32 cols; 4 lanes per row, 16B each
    int srow = wv * 16 + (lane >> 2);
    int scol = (lane & 3) * 8;
    const f16* gA = A + (size_t)(m0 + srow) * K + scol;
    const f16* gB = B + (size_t)(n0 + srow) * K + scol;
    // linear LDS: byte offset = row*64 + (lane&3)*16 = wv*1024 + lane*16
    char* ldsA = (char*)(&As[0][0]) + wv * 1024 + lane * 16;
    char* ldsB = (char*)(&Bs[0][0]) + wv * 1024 + lane * 16;

    f32x4 acc[4][4] = {};

    for (int k0 = 0; k0 < K; k0 += BK) {
        __syncthreads();   // previous compute done before overwriting LDS
        gload_lds16(gA + k0,                 ldsA);
        gload_lds16(gA + (size_t)64 * K + k0, ldsA + 4096);
        gload_lds16(gB + k0,                 ldsB);
        gload_lds16(gB + (size_t)64 * K + k0, ldsB + 4096);
        __syncthreads();   // vmcnt(0) drained before barrier -> LDS ready

        half8 a[4], b[4];
        #pragma unroll
        for (int m = 0; m < 4; ++m)
            a[m] = *reinterpret_cast<const half8*>(
                &As[wr * 64 + m * 16 + (lane & 15)][(lane >> 4) * 8]);
        #pragma unroll
        for (int n = 0; n < 4; ++n)
            b[n] = *reinterpret_cast<const half8*>(
                &Bs[wc * 64 + n * 16 + (lane & 15)][(lane >> 4) * 8]);

        #pragma unroll
        for (int m = 0; m < 4; ++m)
            #pragma unroll
            for (int n = 0; n < 4; ++n)
                acc[m][n] = __builtin_amdgcn_mfma_f32_16x16x32_f16(
                    a[m], b[n], acc[m][n], 0, 0, 0);
    }

    // epilogue: bias + fake-quantize (round-half-even like jnp.round)
    float os  = oscale_p[0];
    float ozp = (float)ozp_p[0];
    float inv = 1.0f / os;
    int rbase = m0 + wr * 64;
    int cbase = n0 + wc * 64;
    #pragma unroll
    for (int n = 0; n < 4; ++n) {
        int col = cbase + n * 16 + (lane & 15);
        float bv = bias[col];
        #pragma unroll
        for (int m = 0; m < 4; ++m) {
            #pragma unroll
            for (int r = 0; r < 4; ++r) {
                int row = rbase + m * 16 + (lane >> 4) * 4 + r;
                float o = acc[m][n][r] + bv;
                float q = rintf(o * inv) + ozp;
                q = fminf(fmaxf(q, 0.0f), 255.0f);
                C[(size_t)row * N + col] = (q - ozp) * os;
            }
        }
    }
}

// ---------------- launch ----------------

extern "C" void kernel_launch(void* const* d_in, const int* in_sizes, int n_in,
                              void* d_out, int out_size, void* d_ws, size_t ws_size,
                              hipStream_t stream) {
    const float* x      = (const float*)d_in[0];
    const int*   w8     = (const int*)d_in[1];
    const float* wscale = (const float*)d_in[2];
    const int*   wzp    = (const int*)d_in[3];
    const float* bias   = (const float*)d_in[4];
    const float* oscale = (const float*)d_in[5];
    const int*   ozp    = (const int*)d_in[6];
    float* out = (float*)d_out;

    const size_t x_elems = (size_t)TOKENS * D_IN;      // 33,554,432
    const size_t w_elems = (size_t)D_OUT * D_IN;       // 16,777,216
    const size_t need = (x_elems + w_elems) * sizeof(f16);  // ~100.7 MB
    if (ws_size < need) return;  // fail loudly (zero output) rather than corrupt

    f16* xh = (f16*)d_ws;
    f16* wh = xh + x_elems;

    {
        int blocks = (int)(x_elems / 4 / 256);
        cvt_x_kernel<<<blocks, 256, 0, stream>>>(x, xh);
    }
    {
        int blocks = (int)(w_elems / 4 / 256);
        cvt_w_kernel<<<blocks, 256, 0, stream>>>(w8, wh, wscale, wzp);
    }
    {
        int grid = (TOKENS / BM) * (D_OUT / BN);       // 64*32 = 2048
        gemm_f16_kernel<<<grid, 256, 0, stream>>>(xh, wh, bias, oscale, ozp, out);
    }
}

// Round 3
// 288.770 us; speedup vs baseline: 1.3886x; 1.3886x over previous
//
#include <hip/hip_runtime.h>

#define TOKENS 8192
#define D_IN   4096
#define D_OUT  4096

typedef _Float16 f16;
typedef __attribute__((ext_vector_type(8))) _Float16 half8;
typedef __attribute__((ext_vector_type(4))) float    f32x4;
typedef __attribute__((address_space(3))) char       lds_char;

// ---------------- conversion kernels ----------------

__global__ void cvt_x_kernel(const float* __restrict__ x, f16* __restrict__ xh) {
    size_t i = ((size_t)blockIdx.x * blockDim.x + threadIdx.x) * 4;
    float4 v = *reinterpret_cast<const float4*>(x + i);
    union { f16 h[4]; uint2 u; } p;
    p.h[0] = (f16)v.x; p.h[1] = (f16)v.y; p.h[2] = (f16)v.z; p.h[3] = (f16)v.w;
    *reinterpret_cast<uint2*>(xh + i) = p.u;
}

__global__ void cvt_w_kernel(const int* __restrict__ w, f16* __restrict__ wh,
                             const float* __restrict__ scale_p,
                             const int* __restrict__ zp_p) {
    size_t i = ((size_t)blockIdx.x * blockDim.x + threadIdx.x) * 4;
    float s = scale_p[0];
    float z = (float)zp_p[0];
    int4 v = *reinterpret_cast<const int4*>(w + i);
    union { f16 h[4]; uint2 u; } p;
    p.h[0] = (f16)(((float)v.x - z) * s);
    p.h[1] = (f16)(((float)v.y - z) * s);
    p.h[2] = (f16)(((float)v.z - z) * s);
    p.h[3] = (f16)(((float)v.w - z) * s);
    *reinterpret_cast<uint2*>(wh + i) = p.u;
}

// ---------------- GEMM: 256x256 tile, BK=64, 8 waves, 8-phase pipeline ----
// C[t][o] = sum_k A[t][k]*B[o][k];  A=[M][K] f16, B=[N][K] f16 (both K-major).
// LDS: 2 dbuf x (A 32KB + B 32KB) = 128 KB. Tiles stored [256][64] f16
// (128 B rows) with XOR swizzle: phys_colbyte = logical_colbyte ^ ((row&7)<<4).
// global_load_lds writes linearly (wave base + lane*16), so the swizzle is
// pre-applied to the per-lane GLOBAL source column (rule 21 / m173).
//
// vmcnt ledger (per wave, steady state): enter tile t with 2 outstanding
// [A-Q1(t), A-Q3(t)]. ph0 +2 (B-Q0/Q1(t+1)) -> 4. ph1 +2 (B-Q2/Q3) -> 6;
// VMCNT(4) drains A-Q1/Q3(t) before ph2 reads them. ph2 +2 (A-Q0/Q2) -> 6.
// ph3 +2 (A-Q1/Q3) -> 8; VMCNT(2) drains B(t+1)+A-Q0/Q2(t+1) before tile
// boundary. LAST TILE IS PEELED: it enters with 2 outstanding and issues
// nothing, so ph1's VMCNT(4) would be a no-op -> needs VMCNT(0)+BAR up front
// (this was the round-2 bug: phase 2 of the last tile read A-Q1/Q3 stale).

#define BM 256
#define BN 256
#define BK 64
#define NT (D_IN / BK)      // 64 K-tiles
#define LDS_BUF   65536     // one dbuf: A[32768] + B[32768]
#define LDS_B_OFF 32768

__device__ __forceinline__ void stage16(const f16* g, lds_char* l) {
    __builtin_amdgcn_global_load_lds(
        (const __attribute__((address_space(1))) void*)g,
        (__attribute__((address_space(3))) void*)l, 16, 0, 0);
}

#define LDS_LOAD8(p) (*(const __attribute__((address_space(3))) half8*)(p))

#define LOAD_A(QM)                                                          \
    do { _Pragma("unroll")                                                  \
        for (int fm = 0; fm < 4; ++fm) {                                    \
            int rr = wr * 128 + (QM) * 64 + fm * 16 + lr;                   \
            _Pragma("unroll")                                               \
            for (int ks = 0; ks < 2; ++ks)                                  \
                a[fm][ks] = LDS_LOAD8(bufA + rr * 128 +                     \
                                      ((cb0 + ks * 64) ^ swzr));            \
        } } while (0)

#define LOAD_B(QN, BV)                                                     \
    do { _Pragma("unroll")                                                  \
        for (int fn = 0; fn < 2; ++fn) {                                    \
            int rr = wc * 64 + (QN) * 32 + fn * 16 + lr;                    \
            _Pragma("unroll")                                               \
            for (int ks = 0; ks < 2; ++ks)                                  \
                BV[fn][ks] = LDS_LOAD8(bufB + rr * 128 +                    \
                                       ((cb0 + ks * 64) ^ swzr));           \
        } } while (0)

#define MFMA_QUAD(QM, QN, BV)                                               \
    do { _Pragma("unroll")                                                  \
        for (int fm = 0; fm < 4; ++fm) {                                    \
            _Pragma("unroll")                                               \
            for (int fn = 0; fn < 2; ++fn) {                                \
                _Pragma("unroll")                                           \
                for (int ks = 0; ks < 2; ++ks)                              \
                    acc[(QM)*4+fm][(QN)*2+fn] =                             \
                        __builtin_amdgcn_mfma_f32_16x16x32_f16(             \
                            a[fm][ks], BV[fn][ks],                          \
                            acc[(QM)*4+fm][(QN)*2+fn], 0, 0, 0);            \
            }                                                               \
        } } while (0)

#define FENCE()    asm volatile("" ::: "memory")
#define BAR()      __builtin_amdgcn_s_barrier()
#define LGKM0()    asm volatile("s_waitcnt lgkmcnt(0)" ::: "memory")
#define VMCNT(N)   asm volatile("s_waitcnt vmcnt(" #N ")" ::: "memory")
#define SCHEDBAR() __builtin_amdgcn_sched_barrier(0)
#define PRIO(x)    __builtin_amdgcn_s_setprio(x)

__global__ __launch_bounds__(512, 2)
void gemm8p(const f16* __restrict__ A, const f16* __restrict__ B,
            const float* __restrict__ bias,
            const float* __restrict__ oscale_p, const int* __restrict__ ozp_p,
            float* __restrict__ C)
{
    __shared__ __align__(1024) char smem_[2 * LDS_BUF];   // 128 KiB (gfx950: 160 max)
    lds_char* smem = (lds_char*)smem_;
    constexpr int K = D_IN, N = D_OUT;

    // XCD-aware bijective swizzle (grid = 512, divisible by 8)
    int nwg = gridDim.x;
    int cpx = nwg >> 3;
    int bid = blockIdx.x;
    int swz = (bid & 7) * cpx + (bid >> 3);
    int ntn = N / BN;                        // 16
    int m0 = (swz / ntn) * BM;
    int n0 = (swz % ntn) * BN;

    int tid = threadIdx.x;
    int l   = tid & 63;
    int wv  = tid >> 6;                      // 0..7
    int wr  = wv >> 2;                       // 0..1 (M)
    int wc  = wv & 3;                        // 0..3 (N)

    // staging: one block-wide call = 64 rows (8 waves x 8 rows x 128 B).
    // lane l -> row_in_block = l>>3, phys slot = l&7;
    // pre-swizzled global col = ((l&7) ^ (l>>3)) * 8 f16.
    int srow = wv * 8 + (l >> 3);
    int scol = ((l & 7) ^ (l >> 3)) * 8;
    const f16* gA = A + (size_t)(m0 + srow) * K + scol;
    const f16* gB = B + (size_t)(n0 + srow) * K + scol;
    lds_char* dstbase = smem + wv * 1024 + l * 16;

    // read-side per-lane constants
    int lr   = l & 15;
    int swzr = (l & 7) << 4;
    int cb0  = (l >> 4) * 16;

    f32x4 acc[8][4] = {};                    // [qm*4+fm][qn*2+fn]

    // ---- prologue: stage tile 0 -> buffer 0, drain, barrier
    #pragma unroll
    for (int q = 0; q < 4; ++q) stage16(gA + (size_t)q * 64 * K, dstbase + q * 8192);
    #pragma unroll
    for (int q = 0; q < 4; ++q) stage16(gB + (size_t)q * 64 * K, dstbase + LDS_B_OFF + q * 8192);
    VMCNT(0);
    BAR();

    half8 a[4][2], b0v[2][2], b1v[2][2];

    for (int t = 0; t < NT - 1; ++t) {
        const lds_char* bufA = smem + (t & 1) * LDS_BUF;
        const lds_char* bufB = bufA + LDS_B_OFF;
        lds_char* dst = dstbase + ((t + 1) & 1) * LDS_BUF;
        const f16* nA = gA + (size_t)(t + 1) * BK;
        const f16* nB = gB + (size_t)(t + 1) * BK;

        // ===== phase 0: quadrant (0,0); stage B-Q0,B-Q1 of t+1 =====
        FENCE();
        LOAD_A(0);
        LOAD_B(0, b0v);
        stage16(nB,                      dst + LDS_B_OFF);
        stage16(nB + (size_t)64 * K,     dst + LDS_B_OFF + 8192);
        BAR(); LGKM0(); SCHEDBAR();
        PRIO(1); MFMA_QUAD(0, 0, b0v); PRIO(0);
        SCHEDBAR();
        BAR();

        // ===== phase 1: quadrant (0,1); stage B-Q2,B-Q3; vmcnt(4) =====
        FENCE();
        LOAD_B(1, b1v);
        stage16(nB + (size_t)128 * K,    dst + LDS_B_OFF + 2 * 8192);
        stage16(nB + (size_t)192 * K,    dst + LDS_B_OFF + 3 * 8192);
        BAR(); LGKM0(); SCHEDBAR();
        PRIO(1); MFMA_QUAD(0, 1, b1v); PRIO(0);
        SCHEDBAR();
        VMCNT(4);     // drains A-Q1/Q3 of CURRENT tile before phase 2 reads
        BAR();

        // ===== phase 2: quadrant (1,1); stage A-Q0,A-Q2 =====
        FENCE();
        LOAD_A(1);
        stage16(nA,                      dst);
        stage16(nA + (size_t)128 * K,    dst + 2 * 8192);
        BAR(); LGKM0(); SCHEDBAR();
        PRIO(1); MFMA_QUAD(1, 1, b1v); PRIO(0);
        SCHEDBAR();
        BAR();

        // ===== phase 3: quadrant (1,0); stage A-Q1,A-Q3; vmcnt(2) =====
        FENCE();
        stage16(nA + (size_t)64 * K,     dst + 8192);
        stage16(nA + (size_t)192 * K,    dst + 3 * 8192);
        BAR(); SCHEDBAR();
        PRIO(1); MFMA_QUAD(1, 0, b0v); PRIO(0);
        SCHEDBAR();
        VMCNT(2);     // drains next tile's B (all) + A-Q0/Q2 before boundary
        BAR();
    }

    // ===== peeled final tile (t = NT-1): no staging, full drain first =====
    {
        const int t = NT - 1;
        const lds_char* bufA = smem + (t & 1) * LDS_BUF;
        const lds_char* bufB = bufA + LDS_B_OFF;

        VMCNT(0);     // A-Q1/Q3 of the final tile still in flight at entry
        BAR();        // collective: every wave's slices resident

        FENCE();
        LOAD_A(0);
        LOAD_B(0, b0v);
        LOAD_B(1, b1v);
        LGKM0(); SCHEDBAR();
        PRIO(1);
        MFMA_QUAD(0, 0, b0v);
        MFMA_QUAD(0, 1, b1v);
        PRIO(0);
        LOAD_A(1);
        LGKM0(); SCHEDBAR();
        PRIO(1);
        MFMA_QUAD(1, 1, b1v);
        MFMA_QUAD(1, 0, b0v);
        PRIO(0);
    }

    // ---- epilogue: bias + fake-quantize (round-half-even = jnp.round)
    float os  = oscale_p[0];
    float ozp = (float)ozp_p[0];
    float inv = 1.0f / os;
    #pragma unroll
    for (int qm = 0; qm < 2; ++qm) {
        #pragma unroll
        for (int fm = 0; fm < 4; ++fm) {
            int rowb = m0 + wr * 128 + qm * 64 + fm * 16 + (l >> 4) * 4;
            #pragma unroll
            for (int qn = 0; qn < 2; ++qn) {
                #pragma unroll
                for (int fn = 0; fn < 2; ++fn) {
                    int col = n0 + wc * 64 + qn * 32 + fn * 16 + lr;
                    float bv = bias[col];
                    f32x4 v = acc[qm * 4 + fm][qn * 2 + fn];
                    #pragma unroll
                    for (int j = 0; j < 4; ++j) {
                        float o = v[j] + bv;
                        float q = rintf(o * inv) + ozp;
                        q = fminf(fmaxf(q, 0.0f), 255.0f);
                        C[(size_t)(rowb + j) * N + col] = (q - ozp) * os;
                    }
                }
            }
        }
    }
}

// ---------------- launch ----------------

extern "C" void kernel_launch(void* const* d_in, const int* in_sizes, int n_in,
                              void* d_out, int out_size, void* d_ws, size_t ws_size,
                              hipStream_t stream) {
    const float* x      = (const float*)d_in[0];
    const int*   w8     = (const int*)d_in[1];
    const float* wscale = (const float*)d_in[2];
    const int*   wzp    = (const int*)d_in[3];
    const float* bias   = (const float*)d_in[4];
    const float* oscale = (const float*)d_in[5];
    const int*   ozp    = (const int*)d_in[6];
    float* out = (float*)d_out;

    const size_t x_elems = (size_t)TOKENS * D_IN;
    const size_t w_elems = (size_t)D_OUT * D_IN;
    const size_t need = (x_elems + w_elems) * sizeof(f16);
    if (ws_size < need) return;

    f16* xh = (f16*)d_ws;
    f16* wh = xh + x_elems;

    {
        int blocks = (int)(x_elems / 4 / 256);
        cvt_x_kernel<<<blocks, 256, 0, stream>>>(x, xh);
    }
    {
        int blocks = (int)(w_elems / 4 / 256);
        cvt_w_kernel<<<blocks, 256, 0, stream>>>(w8, wh, wscale, wzp);
    }
    {
        int grid = (TOKENS / BM) * (D_OUT / BN);   // 32 * 16 = 512, %8 == 0
        gemm8p<<<grid, 512, 0, stream>>>(xh, wh, bias, oscale, ozp, out);
    }
}

// Round 4
// 285.204 us; speedup vs baseline: 1.4060x; 1.0125x over previous
//
#include <hip/hip_runtime.h>

#define TOKENS 8192
#define D_IN   4096
#define D_OUT  4096

typedef _Float16 f16;
typedef __attribute__((ext_vector_type(8))) _Float16 half8;
typedef __attribute__((ext_vector_type(4))) float    f32x4;
typedef __attribute__((address_space(3))) char       lds_char;

// ---------------- conversion kernels ----------------

__global__ void cvt_x_kernel(const float* __restrict__ x, f16* __restrict__ xh) {
    size_t i = ((size_t)blockIdx.x * blockDim.x + threadIdx.x) * 4;
    float4 v = *reinterpret_cast<const float4*>(x + i);
    union { f16 h[4]; uint2 u; } p;
    p.h[0] = (f16)v.x; p.h[1] = (f16)v.y; p.h[2] = (f16)v.z; p.h[3] = (f16)v.w;
    *reinterpret_cast<uint2*>(xh + i) = p.u;
}

__global__ void cvt_w_kernel(const int* __restrict__ w, f16* __restrict__ wh,
                             const float* __restrict__ scale_p,
                             const int* __restrict__ zp_p) {
    size_t i = ((size_t)blockIdx.x * blockDim.x + threadIdx.x) * 4;
    float s = scale_p[0];
    float z = (float)zp_p[0];
    int4 v = *reinterpret_cast<const int4*>(w + i);
    union { f16 h[4]; uint2 u; } p;
    p.h[0] = (f16)(((float)v.x - z) * s);
    p.h[1] = (f16)(((float)v.y - z) * s);
    p.h[2] = (f16)(((float)v.z - z) * s);
    p.h[3] = (f16)(((float)v.w - z) * s);
    *reinterpret_cast<uint2*>(wh + i) = p.u;
}

// ---------------- GEMM: 256x256 tile, BK=64, 8 waves, 8-phase pipeline ----
// C[t][o] = sum_k A[t][k]*B[o][k];  A=[M][K] f16, B=[N][K] f16 (both K-major).
// LDS: 2 dbuf x (A 32KB + B 32KB) = 128 KB. Tiles stored [256][64] f16
// (128 B rows) with XOR swizzle: phys_colbyte = logical_colbyte ^ ((row&7)<<4).
// global_load_lds writes linearly (wave base + lane*16), so the swizzle is
// pre-applied to the per-lane GLOBAL source column (rule 21 / m173).
//
// R4 change: NO manual lgkmcnt(0)/sched_barrier before MFMA clusters — the
// compiler's data-dependence waitcnts are fine-grained (lgkmcnt(11..0)), so
// each wave starts MFMA as soon as its first fragments land and hides its
// remaining ds_reads under compute. Manual full-drain serialized ds-read
// service time with MFMA time (R3: MfmaUtil 46%, ~2600 extra cyc/tile).
//
// vmcnt ledger (per wave, steady state): enter tile t with 2 outstanding
// [A-Q1(t), A-Q3(t)]. ph0 +2 (B-Q0/Q1(t+1)) -> 4. ph1 +2 (B-Q2/Q3) -> 6;
// VMCNT(4) drains A-Q1/Q3(t) before ph2 reads them. ph2 +2 (A-Q0/Q2) -> 6.
// ph3 +2 (A-Q1/Q3) -> 8; VMCNT(2) drains B(t+1)+A-Q0/Q2(t+1) before tile
// boundary. LAST TILE IS PEELED (enters with 2 outstanding, issues nothing):
// VMCNT(0)+BAR up front.

#define BM 256
#define BN 256
#define BK 64
#define NT (D_IN / BK)      // 64 K-tiles
#define LDS_BUF   65536     // one dbuf: A[32768] + B[32768]
#define LDS_B_OFF 32768

__device__ __forceinline__ void stage16(const f16* g, lds_char* l) {
    __builtin_amdgcn_global_load_lds(
        (const __attribute__((address_space(1))) void*)g,
        (__attribute__((address_space(3))) void*)l, 16, 0, 0);
}

#define LDS_LOAD8(p) (*(const __attribute__((address_space(3))) half8*)(p))

#define LOAD_A(QM)                                                          \
    do { _Pragma("unroll")                                                  \
        for (int fm = 0; fm < 4; ++fm) {                                    \
            int rr = wr * 128 + (QM) * 64 + fm * 16 + lr;                   \
            _Pragma("unroll")                                               \
            for (int ks = 0; ks < 2; ++ks)                                  \
                a[fm][ks] = LDS_LOAD8(bufA + rr * 128 +                     \
                                      ((cb0 + ks * 64) ^ swzr));            \
        } } while (0)

#define LOAD_B(QN, BV)                                                     \
    do { _Pragma("unroll")                                                  \
        for (int fn = 0; fn < 2; ++fn) {                                    \
            int rr = wc * 64 + (QN) * 32 + fn * 16 + lr;                    \
            _Pragma("unroll")                                               \
            for (int ks = 0; ks < 2; ++ks)                                  \
                BV[fn][ks] = LDS_LOAD8(bufB + rr * 128 +                    \
                                       ((cb0 + ks * 64) ^ swzr));           \
        } } while (0)

#define MFMA_QUAD(QM, QN, BV)                                               \
    do { _Pragma("unroll")                                                  \
        for (int fm = 0; fm < 4; ++fm) {                                    \
            _Pragma("unroll")                                               \
            for (int fn = 0; fn < 2; ++fn) {                                \
                _Pragma("unroll")                                           \
                for (int ks = 0; ks < 2; ++ks)                              \
                    acc[(QM)*4+fm][(QN)*2+fn] =                             \
                        __builtin_amdgcn_mfma_f32_16x16x32_f16(             \
                            a[fm][ks], BV[fn][ks],                          \
                            acc[(QM)*4+fm][(QN)*2+fn], 0, 0, 0);            \
            }                                                               \
        } } while (0)

#define FENCE()    asm volatile("" ::: "memory")
#define BAR()      __builtin_amdgcn_s_barrier()
#define VMCNT(N)   asm volatile("s_waitcnt vmcnt(" #N ")" ::: "memory")
#define PRIO(x)    __builtin_amdgcn_s_setprio(x)

__global__ __launch_bounds__(512, 2)
void gemm8p(const f16* __restrict__ A, const f16* __restrict__ B,
            const float* __restrict__ bias,
            const float* __restrict__ oscale_p, const int* __restrict__ ozp_p,
            float* __restrict__ C)
{
    __shared__ __align__(1024) char smem_[2 * LDS_BUF];   // 128 KiB (gfx950: 160 max)
    lds_char* smem = (lds_char*)smem_;
    constexpr int K = D_IN, N = D_OUT;

    // XCD-aware bijective swizzle (grid = 512, divisible by 8)
    int nwg = gridDim.x;
    int cpx = nwg >> 3;
    int bid = blockIdx.x;
    int swz = (bid & 7) * cpx + (bid >> 3);
    int ntn = N / BN;                        // 16
    int m0 = (swz / ntn) * BM;
    int n0 = (swz % ntn) * BN;

    int tid = threadIdx.x;
    int l   = tid & 63;
    int wv  = tid >> 6;                      // 0..7
    int wr  = wv >> 2;                       // 0..1 (M)
    int wc  = wv & 3;                        // 0..3 (N)

    // staging: one block-wide call = 64 rows (8 waves x 8 rows x 128 B).
    // lane l -> row_in_block = l>>3, phys slot = l&7;
    // pre-swizzled global col = ((l&7) ^ (l>>3)) * 8 f16.
    int srow = wv * 8 + (l >> 3);
    int scol = ((l & 7) ^ (l >> 3)) * 8;
    const f16* gA = A + (size_t)(m0 + srow) * K + scol;
    const f16* gB = B + (size_t)(n0 + srow) * K + scol;
    lds_char* dstbase = smem + wv * 1024 + l * 16;

    // read-side per-lane constants
    int lr   = l & 15;
    int swzr = (l & 7) << 4;
    int cb0  = (l >> 4) * 16;

    f32x4 acc[8][4] = {};                    // [qm*4+fm][qn*2+fn]

    // ---- prologue: stage tile 0 -> buffer 0, drain, barrier
    #pragma unroll
    for (int q = 0; q < 4; ++q) stage16(gA + (size_t)q * 64 * K, dstbase + q * 8192);
    #pragma unroll
    for (int q = 0; q < 4; ++q) stage16(gB + (size_t)q * 64 * K, dstbase + LDS_B_OFF + q * 8192);
    VMCNT(0);
    BAR();

    half8 a[4][2], b0v[2][2], b1v[2][2];

    for (int t = 0; t < NT - 1; ++t) {
        const lds_char* bufA = smem + (t & 1) * LDS_BUF;
        const lds_char* bufB = bufA + LDS_B_OFF;
        lds_char* dst = dstbase + ((t + 1) & 1) * LDS_BUF;
        const f16* nA = gA + (size_t)(t + 1) * BK;
        const f16* nB = gB + (size_t)(t + 1) * BK;

        // ===== phase 0: quadrant (0,0); stage B-Q0,B-Q1 of t+1 =====
        FENCE();
        LOAD_A(0);
        LOAD_B(0, b0v);
        stage16(nB,                      dst + LDS_B_OFF);
        stage16(nB + (size_t)64 * K,     dst + LDS_B_OFF + 8192);
        BAR();
        PRIO(1); MFMA_QUAD(0, 0, b0v); PRIO(0);
        BAR();

        // ===== phase 1: quadrant (0,1); stage B-Q2,B-Q3; vmcnt(4) =====
        FENCE();
        LOAD_B(1, b1v);
        stage16(nB + (size_t)128 * K,    dst + LDS_B_OFF + 2 * 8192);
        stage16(nB + (size_t)192 * K,    dst + LDS_B_OFF + 3 * 8192);
        BAR();
        PRIO(1); MFMA_QUAD(0, 1, b1v); PRIO(0);
        VMCNT(4);     // drains A-Q1/Q3 of CURRENT tile before phase 2 reads
        BAR();

        // ===== phase 2: quadrant (1,1); stage A-Q0,A-Q2 =====
        FENCE();
        LOAD_A(1);
        stage16(nA,                      dst);
        stage16(nA + (size_t)128 * K,    dst + 2 * 8192);
        BAR();
        PRIO(1); MFMA_QUAD(1, 1, b1v); PRIO(0);
        BAR();

        // ===== phase 3: quadrant (1,0); stage A-Q1,A-Q3; vmcnt(2) =====
        FENCE();
        stage16(nA + (size_t)64 * K,     dst + 8192);
        stage16(nA + (size_t)192 * K,    dst + 3 * 8192);
        BAR();
        PRIO(1); MFMA_QUAD(1, 0, b0v); PRIO(0);
        VMCNT(2);     // drains next tile's B (all) + A-Q0/Q2 before boundary
        BAR();
    }

    // ===== peeled final tile (t = NT-1): no staging, full drain first =====
    {
        const int t = NT - 1;
        const lds_char* bufA = smem + (t & 1) * LDS_BUF;
        const lds_char* bufB = bufA + LDS_B_OFF;

        VMCNT(0);     // A-Q1/Q3 of the final tile still in flight at entry
        BAR();        // collective: every wave's slices resident

        FENCE();
        LOAD_A(0);
        LOAD_B(0, b0v);
        LOAD_B(1, b1v);
        PRIO(1);
        MFMA_QUAD(0, 0, b0v);
        MFMA_QUAD(0, 1, b1v);
        PRIO(0);
        LOAD_A(1);
        PRIO(1);
        MFMA_QUAD(1, 1, b1v);
        MFMA_QUAD(1, 0, b0v);
        PRIO(0);
    }

    // ---- epilogue: bias + fake-quantize (round-half-even = jnp.round)
    float os  = oscale_p[0];
    float ozp = (float)ozp_p[0];
    float inv = 1.0f / os;
    #pragma unroll
    for (int qm = 0; qm < 2; ++qm) {
        #pragma unroll
        for (int fm = 0; fm < 4; ++fm) {
            int rowb = m0 + wr * 128 + qm * 64 + fm * 16 + (l >> 4) * 4;
            #pragma unroll
            for (int qn = 0; qn < 2; ++qn) {
                #pragma unroll
                for (int fn = 0; fn < 2; ++fn) {
                    int col = n0 + wc * 64 + qn * 32 + fn * 16 + lr;
                    float bv = bias[col];
                    f32x4 v = acc[qm * 4 + fm][qn * 2 + fn];
                    #pragma unroll
                    for (int j = 0; j < 4; ++j) {
                        float o = v[j] + bv;
                        float q = rintf(o * inv) + ozp;
                        q = fminf(fmaxf(q, 0.0f), 255.0f);
                        C[(size_t)(rowb + j) * N + col] = (q - ozp) * os;
                    }
                }
            }
        }
    }
}

// ---------------- launch ----------------

extern "C" void kernel_launch(void* const* d_in, const int* in_sizes, int n_in,
                              void* d_out, int out_size, void* d_ws, size_t ws_size,
                              hipStream_t stream) {
    const float* x      = (const float*)d_in[0];
    const int*   w8     = (const int*)d_in[1];
    const float* wscale = (const float*)d_in[2];
    const int*   wzp    = (const int*)d_in[3];
    const float* bias   = (const float*)d_in[4];
    const float* oscale = (const float*)d_in[5];
    const int*   ozp    = (const int*)d_in[6];
    float* out = (float*)d_out;

    const size_t x_elems = (size_t)TOKENS * D_IN;
    const size_t w_elems = (size_t)D_OUT * D_IN;
    const size_t need = (x_elems + w_elems) * sizeof(f16);
    if (ws_size < need) return;

    f16* xh = (f16*)d_ws;
    f16* wh = xh + x_elems;

    {
        int blocks = (int)(x_elems / 4 / 256);
        cvt_x_kernel<<<blocks, 256, 0, stream>>>(x, xh);
    }
    {
        int blocks = (int)(w_elems / 4 / 256);
        cvt_w_kernel<<<blocks, 256, 0, stream>>>(w8, wh, wscale, wzp);
    }
    {
        int grid = (TOKENS / BM) * (D_OUT / BN);   // 32 * 16 = 512, %8 == 0
        gemm8p<<<grid, 512, 0, stream>>>(xh, wh, bias, oscale, ozp, out);
    }
}

// Round 6
// 282.953 us; speedup vs baseline: 1.4172x; 1.0080x over previous
//
#include <hip/hip_runtime.h>

#define TOKENS 8192
#define D_IN   4096
#define D_OUT  4096

typedef _Float16 f16;
typedef __attribute__((ext_vector_type(8))) _Float16 half8;
typedef __attribute__((ext_vector_type(4))) float    f32x4;
typedef __attribute__((address_space(3))) char       lds_char;

// ---------------- conversion kernels ----------------

__global__ void cvt_x_kernel(const float* __restrict__ x, f16* __restrict__ xh) {
    size_t i = ((size_t)blockIdx.x * blockDim.x + threadIdx.x) * 4;
    float4 v = *reinterpret_cast<const float4*>(x + i);
    union { f16 h[4]; uint2 u; } p;
    p.h[0] = (f16)v.x; p.h[1] = (f16)v.y; p.h[2] = (f16)v.z; p.h[3] = (f16)v.w;
    *reinterpret_cast<uint2*>(xh + i) = p.u;
}

__global__ void cvt_w_kernel(const int* __restrict__ w, f16* __restrict__ wh,
                             const float* __restrict__ scale_p,
                             const int* __restrict__ zp_p) {
    size_t i = ((size_t)blockIdx.x * blockDim.x + threadIdx.x) * 4;
    float s = scale_p[0];
    float z = (float)zp_p[0];
    int4 v = *reinterpret_cast<const int4*>(w + i);
    union { f16 h[4]; uint2 u; } p;
    p.h[0] = (f16)(((float)v.x - z) * s);
    p.h[1] = (f16)(((float)v.y - z) * s);
    p.h[2] = (f16)(((float)v.z - z) * s);
    p.h[3] = (f16)(((float)v.w - z) * s);
    *reinterpret_cast<uint2*>(wh + i) = p.u;
}

// ---------------- GEMM: 256x256 tile, BK=64, 8 waves ----------------------
// C[t][o] = sum_k A[t][k]*B[o][k];  A=[M][K] f16, B=[N][K] f16 (both K-major).
// LDS: 2 dbuf x (A 32KB + B 32KB) = 128 KB, [256][64] f16 rows with XOR
// swizzle phys_colbyte = logical ^ ((row&7)<<4); global_load_lds writes
// linearly, swizzle pre-applied to the per-lane GLOBAL source column.
//
// COLLECTIVE-STAGING PROTOCOL (R5 post-mortem): before ANY wave ds_reads a
// staged region, the staging waves must drain their own vmcnt AND a barrier
// must separate drain from read:   drain (VMCNT) -> s_barrier -> ds_read.
// R5 broke this exactly once (phase 2: VMCNT(4); LOAD_A(1) with no BAR
// between) -> absmax 36. R6 adds that single BAR back. All other consume
// sites already follow the protocol (boundary VMCNT(2);BAR, peel VMCNT(0);
// BAR).
//
// vmcnt ledger (per wave, steady state): enter tile t with 2 outstanding
// [A13(t), staged during t-1 ph3]. ph0 +B01(t+1) -> 4. ph1 +B23(t+1) -> 6.
// ph2: VMCNT(4) drains A13(t); BAR; reads A-Q1/Q3; +A02(t+1) -> 6.
// ph3: FENCE (keeps A13 stages issued after A02 -> counted drain covers the
// right ops); +A13(t+1) -> 8. boundary: VMCNT(2) drains B01/B23/A02(t+1),
// leaves A13(t+1); BAR. Last tile peeled: VMCNT(0)+BAR at entry.

#define BM 256
#define BN 256
#define BK 64
#define NT (D_IN / BK)      // 64 K-tiles
#define LDS_BUF   65536
#define LDS_B_OFF 32768

__device__ __forceinline__ void stage16(const f16* g, lds_char* l) {
    __builtin_amdgcn_global_load_lds(
        (const __attribute__((address_space(1))) void*)g,
        (__attribute__((address_space(3))) void*)l, 16, 0, 0);
}

#define LDS_LOAD8(p) (*(const __attribute__((address_space(3))) half8*)(p))

#define LOAD_A(QM)                                                          \
    do { _Pragma("unroll")                                                  \
        for (int fm = 0; fm < 4; ++fm) {                                    \
            int rr = wr * 128 + (QM) * 64 + fm * 16 + lr;                   \
            _Pragma("unroll")                                               \
            for (int ks = 0; ks < 2; ++ks)                                  \
                a[fm][ks] = LDS_LOAD8(bufA + rr * 128 +                     \
                                      ((cb0 + ks * 64) ^ swzr));            \
        } } while (0)

#define LOAD_B(QN, BV)                                                     \
    do { _Pragma("unroll")                                                  \
        for (int fn = 0; fn < 2; ++fn) {                                    \
            int rr = wc * 64 + (QN) * 32 + fn * 16 + lr;                    \
            _Pragma("unroll")                                               \
            for (int ks = 0; ks < 2; ++ks)                                  \
                BV[fn][ks] = LDS_LOAD8(bufB + rr * 128 +                    \
                                       ((cb0 + ks * 64) ^ swzr));           \
        } } while (0)

#define MFMA_QUAD(QM, QN, BV)                                               \
    do { _Pragma("unroll")                                                  \
        for (int fm = 0; fm < 4; ++fm) {                                    \
            _Pragma("unroll")                                               \
            for (int fn = 0; fn < 2; ++fn) {                                \
                _Pragma("unroll")                                           \
                for (int ks = 0; ks < 2; ++ks)                              \
                    acc[(QM)*4+fm][(QN)*2+fn] =                             \
                        __builtin_amdgcn_mfma_f32_16x16x32_f16(             \
                            a[fm][ks], BV[fn][ks],                          \
                            acc[(QM)*4+fm][(QN)*2+fn], 0, 0, 0);            \
            }                                                               \
        } } while (0)

#define FENCE()    asm volatile("" ::: "memory")
#define BAR()      __builtin_amdgcn_s_barrier()
#define VMCNT(N)   asm volatile("s_waitcnt vmcnt(" #N ")" ::: "memory")
#define PRIO(x)    __builtin_amdgcn_s_setprio(x)

__global__ __launch_bounds__(512, 2)
void gemm8p(const f16* __restrict__ A, const f16* __restrict__ B,
            const float* __restrict__ bias,
            const float* __restrict__ oscale_p, const int* __restrict__ ozp_p,
            float* __restrict__ C)
{
    __shared__ __align__(1024) char smem_[2 * LDS_BUF];   // 128 KiB
    lds_char* smem = (lds_char*)smem_;
    constexpr int K = D_IN, N = D_OUT;

    // XCD-aware bijective swizzle (grid = 512, divisible by 8)
    int nwg = gridDim.x;
    int cpx = nwg >> 3;
    int bid = blockIdx.x;
    int swz = (bid & 7) * cpx + (bid >> 3);
    int ntn = N / BN;                        // 16
    int m0 = (swz / ntn) * BM;
    int n0 = (swz % ntn) * BN;

    int tid = threadIdx.x;
    int l   = tid & 63;
    int wv  = tid >> 6;                      // 0..7
    int wr  = wv >> 2;                       // 0..1 (M)
    int wc  = wv & 3;                        // 0..3 (N)

    // staging: lane l -> row_in_block = l>>3, phys slot = l&7;
    // pre-swizzled global col = ((l&7) ^ (l>>3)) * 8 f16.
    int srow = wv * 8 + (l >> 3);
    int scol = ((l & 7) ^ (l >> 3)) * 8;
    const f16* gA = A + (size_t)(m0 + srow) * K + scol;
    const f16* gB = B + (size_t)(n0 + srow) * K + scol;
    lds_char* dstbase = smem + wv * 1024 + l * 16;

    // read-side per-lane constants
    int lr   = l & 15;
    int swzr = (l & 7) << 4;
    int cb0  = (l >> 4) * 16;

    f32x4 acc[8][4] = {};                    // [qm*4+fm][qn*2+fn]

    // ---- prologue: stage tile 0 -> buffer 0, drain, barrier
    #pragma unroll
    for (int q = 0; q < 4; ++q) stage16(gA + (size_t)q * 64 * K, dstbase + q * 8192);
    #pragma unroll
    for (int q = 0; q < 4; ++q) stage16(gB + (size_t)q * 64 * K, dstbase + LDS_B_OFF + q * 8192);
    VMCNT(0);
    BAR();

    half8 a[4][2], b0v[2][2], b1v[2][2];

    for (int t = 0; t < NT - 1; ++t) {
        const lds_char* bufA = smem + (t & 1) * LDS_BUF;
        const lds_char* bufB = bufA + LDS_B_OFF;
        lds_char* dst = dstbase + ((t + 1) & 1) * LDS_BUF;
        const f16* nA = gA + (size_t)(t + 1) * BK;
        const f16* nB = gB + (size_t)(t + 1) * BK;

        // ---- phase 0: reads for quad (0,0); stage B01(t+1)
        LOAD_A(0);
        LOAD_B(0, b0v);
        stage16(nB,                      dst + LDS_B_OFF);
        stage16(nB + (size_t)64 * K,     dst + LDS_B_OFF + 8192);
        BAR();
        PRIO(1); MFMA_QUAD(0, 0, b0v); PRIO(0);

        // ---- phase 1: B1 reads merge into (0,0)'s shadow; stage B23(t+1)
        LOAD_B(1, b1v);
        stage16(nB + (size_t)128 * K,    dst + LDS_B_OFF + 2 * 8192);
        stage16(nB + (size_t)192 * K,    dst + LDS_B_OFF + 3 * 8192);
        BAR();
        PRIO(1); MFMA_QUAD(0, 1, b1v); PRIO(0);

        // ---- phase 2: A13(t) consume point. Protocol: drain own vmcnt,
        // THEN barrier (all waves drained), THEN read. (R5 bug: no BAR here.)
        VMCNT(4);
        BAR();
        LOAD_A(1);
        stage16(nA,                      dst);
        stage16(nA + (size_t)128 * K,    dst + 2 * 8192);
        BAR();
        PRIO(1); MFMA_QUAD(1, 1, b1v); PRIO(0);

        // ---- phase 3: stage A13(t+1) (fenced after A02 for ledger order)
        FENCE();
        stage16(nA + (size_t)64 * K,     dst + 8192);
        stage16(nA + (size_t)192 * K,    dst + 3 * 8192);
        BAR();
        PRIO(1); MFMA_QUAD(1, 0, b0v); PRIO(0);

        // ---- tile boundary: drain next tile's B + A02, barrier, proceed
        VMCNT(2);
        BAR();
    }

    // ===== peeled final tile (t = NT-1): no staging, full drain first =====
    {
        const int t = NT - 1;
        const lds_char* bufA = smem + (t & 1) * LDS_BUF;
        const lds_char* bufB = bufA + LDS_B_OFF;

        VMCNT(0);     // A13 of the final tile still in flight at entry
        BAR();        // collective: every wave's slices resident

        LOAD_A(0);
        LOAD_B(0, b0v);
        LOAD_B(1, b1v);
        PRIO(1);
        MFMA_QUAD(0, 0, b0v);
        MFMA_QUAD(0, 1, b1v);
        PRIO(0);
        LOAD_A(1);
        PRIO(1);
        MFMA_QUAD(1, 1, b1v);
        MFMA_QUAD(1, 0, b0v);
        PRIO(0);
    }

    // ---- epilogue: bias + fake-quantize (round-half-even = jnp.round)
    float os  = oscale_p[0];
    float ozp = (float)ozp_p[0];
    float inv = 1.0f / os;
    #pragma unroll
    for (int qm = 0; qm < 2; ++qm) {
        #pragma unroll
        for (int fm = 0; fm < 4; ++fm) {
            int rowb = m0 + wr * 128 + qm * 64 + fm * 16 + (l >> 4) * 4;
            #pragma unroll
            for (int qn = 0; qn < 2; ++qn) {
                #pragma unroll
                for (int fn = 0; fn < 2; ++fn) {
                    int col = n0 + wc * 64 + qn * 32 + fn * 16 + lr;
                    float bv = bias[col];
                    f32x4 v = acc[qm * 4 + fm][qn * 2 + fn];
                    #pragma unroll
                    for (int j = 0; j < 4; ++j) {
                        float o = v[j] + bv;
                        float q = rintf(o * inv) + ozp;
                        q = fminf(fmaxf(q, 0.0f), 255.0f);
                        C[(size_t)(rowb + j) * N + col] = (q - ozp) * os;
                    }
                }
            }
        }
    }
}

// ---------------- launch ----------------

extern "C" void kernel_launch(void* const* d_in, const int* in_sizes, int n_in,
                              void* d_out, int out_size, void* d_ws, size_t ws_size,
                              hipStream_t stream) {
    const float* x      = (const float*)d_in[0];
    const int*   w8     = (const int*)d_in[1];
    const float* wscale = (const float*)d_in[2];
    const int*   wzp    = (const int*)d_in[3];
    const float* bias   = (const float*)d_in[4];
    const float* oscale = (const float*)d_in[5];
    const int*   ozp    = (const int*)d_in[6];
    float* out = (float*)d_out;

    const size_t x_elems = (size_t)TOKENS * D_IN;
    const size_t w_elems = (size_t)D_OUT * D_IN;
    const size_t need = (x_elems + w_elems) * sizeof(f16);
    if (ws_size < need) return;

    f16* xh = (f16*)d_ws;
    f16* wh = xh + x_elems;

    {
        int blocks = (int)(x_elems / 4 / 256);
        cvt_x_kernel<<<blocks, 256, 0, stream>>>(x, xh);
    }
    {
        int blocks = (int)(w_elems / 4 / 256);
        cvt_w_kernel<<<blocks, 256, 0, stream>>>(w8, wh, wscale, wzp);
    }
    {
        int grid = (TOKENS / BM) * (D_OUT / BN);   // 32 * 16 = 512, %8 == 0
        gemm8p<<<grid, 512, 0, stream>>>(xh, wh, bias, oscale, ozp, out);
    }
}